// Round 1
// baseline (7169.456 us; speedup 1.0000x reference)
//
#include <hip/hip_runtime.h>
#include <cstdint>
#include <cstddef>

// PlainRNN fused: h_{t+1} = tanh(h_t @ W_eff + b_eff), traj[t] = h_t @ W_h2o + b_h2o
// W_eff = W_h2h + W_h2o @ W_i2h  (recurrence composition removes x from the loop)
//
// Persistent kernel: 16 groups (16 batch rows each) x 16 blocks (72 of 1152 cols each).
// W fragments live in VGPRs for all 511 steps; per-step traffic is only the 32KB h tile
// per block + a group-local atomic barrier.

#define BATCH  256
#define INPUT  128
#define HIDDEN 1024
#define OUTPUT 128
#define TSTEPS 512
#define NCAT   1152
#define NTILE  72
#define GROUPS 16
#define MEMB   16

// workspace layout (bytes)
#define WS_WFRAG 0u
#define WS_BEFF  2621440u
#define WS_HBUF  2629632u
#define WS_BAR   3678208u

typedef _Float16 f16;
typedef _Float16 v8h __attribute__((ext_vector_type(8)));
typedef float    v4f __attribute__((ext_vector_type(4)));

__device__ __forceinline__ float fast_tanh(float x){
  // |x| <= ~34 here, no overflow: e^(2x) finite in f32
  float e = __expf(2.0f * x);
  return (e - 1.0f) / (e + 1.0f);
}

// ---- bias composition: beff[0..1023] = b_i2h + b_h2h + b_h2o @ W_i2h ; [1024..1151] = b_h2o ; pad 0
__global__ void k_bias(const float* __restrict__ bi2h, const float* __restrict__ bh2h,
                       const float* __restrict__ bh2o, const float* __restrict__ Wi2h,
                       float* __restrict__ beff){
  int n = blockIdx.x*256 + threadIdx.x;
  if (n >= 1168) return;
  float v = 0.f;
  if (n < HIDDEN){
    v = bi2h[n] + bh2h[n];
    for (int j=0;j<INPUT;j++) v += bh2o[j]*Wi2h[j*HIDDEN + n];
  } else if (n < NCAT){
    v = bh2o[n - HIDDEN];
  }
  beff[n] = v;
}

// ---- h_1 = tanh(x0 @ W_i2h + b_i2h + b_h2h) -> hbuf[0], f16 row-major [256][1024]
__global__ void k_h1(const float* __restrict__ x0, const float* __restrict__ Wi2h,
                     const float* __restrict__ bi2h, const float* __restrict__ bh2h,
                     f16* __restrict__ hbuf){
  int idx = blockIdx.x*256 + threadIdx.x;   // 0..262143 == m*1024+n
  int m = idx >> 10, n = idx & 1023;
  float acc = bi2h[n] + bh2h[n];
  const float* xr = x0 + m*INPUT;
  for (int j=0;j<INPUT;j++) acc += xr[j]*Wi2h[j*HIDDEN + n];
  hbuf[idx] = (f16)fast_tanh(acc);
}

// ---- traj[0] = x_0
__global__ void k_copy0(const float* __restrict__ x0, float* __restrict__ out){
  int i = blockIdx.x*256 + threadIdx.x;
  out[i] = x0[i];
}

// ---- W fragment packing.
// Fragment layout: [mem 16][wave 4][kk 8][c 5][lane 64][8 halves]
// element j of frag = Wcat[k][n], k = wave*256 + kk*32 + (lane>>4)*8 + j,
//                     n = mem*72 + c*16 + (lane&15)   (n>=1152 -> 0)
__global__ void k_wfrag(const float* __restrict__ Wh2h, const float* __restrict__ Wh2o,
                        const float* __restrict__ Wi2h, f16* __restrict__ Wfrag){
  int gid = blockIdx.x*256 + threadIdx.x;     // 0..163839
  int lane = gid & 63;
  int fi = gid >> 6;
  int c = fi % 5, kk = (fi/5) & 7, wv = (fi/40) & 3, mem = fi/160;
  int k0 = wv*256 + kk*32 + (lane>>4)*8;
  int n  = mem*NTILE + c*16 + (lane & 15);
  f16 vals[8];
  if (n >= NCAT){
    #pragma unroll
    for (int j=0;j<8;j++) vals[j] = (f16)0.f;
  } else if (n >= HIDDEN){
    #pragma unroll
    for (int j=0;j<8;j++) vals[j] = (f16)Wh2o[(k0+j)*OUTPUT + (n-HIDDEN)];
  } else {
    float acc[8];
    #pragma unroll
    for (int j=0;j<8;j++) acc[j] = Wh2h[(k0+j)*HIDDEN + n];
    for (int q=0;q<INPUT;q++){
      float wi = Wi2h[q*HIDDEN + n];
      #pragma unroll
      for (int j=0;j<8;j++) acc[j] += Wh2o[(k0+j)*OUTPUT + q]*wi;
    }
    #pragma unroll
    for (int j=0;j<8;j++) vals[j] = (f16)acc[j];
  }
  v8h pack;
  #pragma unroll
  for (int j=0;j<8;j++) pack[j] = vals[j];
  *(v8h*)(Wfrag + (size_t)gid*8) = pack;
}

// ---- persistent recurrence kernel: 256 blocks x 256 threads, 1 block/CU (forced via 96KB dyn LDS)
__global__ void __launch_bounds__(256, 1)
k_rnn(const f16* __restrict__ Wfrag, const float* __restrict__ beff,
      f16* __restrict__ hbuf, unsigned int* __restrict__ bar,
      float* __restrict__ out){
  extern __shared__ char lds_raw[];
  float* red = (float*)lds_raw;   // [(c*3+rank)][lane][4] f32, 15360 B used

  const int tid  = threadIdx.x;
  const int lane = tid & 63;
  const int wv   = tid >> 6;
  const int bid  = blockIdx.x;
  // group-mates share bid&7 -> same XCD under round-robin block->XCD mapping (perf heuristic only)
  const int g    = ((bid & 7) << 1) | (bid >> 7);
  const int mem  = (bid >> 3) & 15;
  const int m0   = g * 16;
  const int n0   = mem * NTILE;
  const int quad = lane >> 4;
  const int l15  = lane & 15;

  // B fragments resident in registers for the whole 511-step loop (160 VGPRs)
  v8h bw[8][5];
  {
    const f16* wp = Wfrag + ((size_t)((mem*4 + wv)*40)*64 + lane)*8;
    #pragma unroll
    for (int kk=0;kk<8;kk++)
      #pragma unroll
      for (int c=0;c<5;c++)
        bw[kk][c] = *(const v8h*)(wp + (size_t)((kk*5+c)*64)*8);
  }

  const int kbase = wv*256;          // this wave's K slice
  unsigned int* cnt = bar + g*32;    // one 128B line per group

  for (int t=1; t<TSTEPS; ++t){
    const f16* hin  = hbuf + (size_t)((t-1)&1)*(BATCH*HIDDEN);
    f16*       hout = hbuf + (size_t)(t&1)*(BATCH*HIDDEN);

    // A fragments: lane holds A[m=lane&15][k=quad*8+j]; waves read disjoint K ranges
    v8h af[8];
    const f16* abase = hin + (size_t)(m0 + l15)*HIDDEN + kbase + quad*8;
    #pragma unroll
    for (int kk=0;kk<8;kk++)
      af[kk] = *(const v8h*)(abase + kk*32);

    v4f acc[5];
    #pragma unroll
    for (int c=0;c<5;c++){ v4f z = {0.f,0.f,0.f,0.f}; acc[c] = z; }

    #pragma unroll
    for (int kk=0;kk<8;kk++){
      #pragma unroll
      for (int c=0;c<5;c++)
        acc[c] = __builtin_amdgcn_mfma_f32_16x16x32_f16(af[kk], bw[kk][c], acc[c], 0,0,0);
    }

    // cross-wave K reduction via LDS. tile c owner = c&3.
    __syncthreads();   // red[] free: previous step fully retired behind the group barrier
    #pragma unroll
    for (int c=0;c<5;c++){
      int owner = c & 3;
      if (wv != owner){
        int rank = (wv > owner) ? wv-1 : wv;
        *(v4f*)(red + ((size_t)(c*3 + rank)*64 + lane)*4) = acc[c];
      }
    }
    __syncthreads();

    // pass 1: hidden columns (consumed by group next step) -> store ASAP
    #pragma unroll
    for (int c=0;c<5;c++){
      if ((c & 3) == wv){
        int colT = c*16 + l15;
        int col  = n0 + colT;
        if (col < HIDDEN && colT < NTILE){
          v4f s = acc[c];
          #pragma unroll
          for (int r=0;r<3;r++) s += *(const v4f*)(red + ((size_t)(c*3 + r)*64 + lane)*4);
          float b = beff[col];
          #pragma unroll
          for (int r=0;r<4;r++){
            float v = fast_tanh(s[r] + b);
            // C/D layout: col=lane&15, row=quad*4+r
            hout[(size_t)(m0 + quad*4 + r)*HIDDEN + col] = (f16)v;
          }
        }
      }
    }
    __syncthreads();                 // drains vmcnt: all h stores complete in L2
    if (tid == 0){
      __threadfence();               // release: make h visible device-wide
      atomicAdd(cnt, 1u);            // arrive
    }
    // pass 2: y columns (consumed by nobody) — overlaps other blocks' arrival
    #pragma unroll
    for (int c=0;c<5;c++){
      if ((c & 3) == wv){
        int colT = c*16 + l15;
        int col  = n0 + colT;
        if (col >= HIDDEN && colT < NTILE){
          v4f s = acc[c];
          #pragma unroll
          for (int r=0;r<3;r++) s += *(const v4f*)(red + ((size_t)(c*3 + r)*64 + lane)*4);
          float b = beff[col];
          float* op = out + (size_t)t*(BATCH*OUTPUT) + (col - HIDDEN);
          #pragma unroll
          for (int r=0;r<4;r++)
            op[(size_t)(m0 + quad*4 + r)*OUTPUT] = s[r] + b;
        }
      }
    }
    if (tid == 0){
      while (__hip_atomic_load(cnt, __ATOMIC_RELAXED, __HIP_MEMORY_SCOPE_AGENT)
             < (unsigned)(MEMB*t)) { __builtin_amdgcn_s_sleep(1); }
      __threadfence();               // acquire: invalidate stale cached h
    }
    __syncthreads();
  }
}

extern "C" void kernel_launch(void* const* d_in, const int* in_sizes, int n_in,
                              void* d_out, int out_size, void* d_ws, size_t ws_size,
                              hipStream_t stream){
  const float* x0   = (const float*)d_in[0];
  const float* Wi2h = (const float*)d_in[1];
  const float* bi2h = (const float*)d_in[2];
  const float* Wh2h = (const float*)d_in[3];
  const float* bh2h = (const float*)d_in[4];
  const float* Wh2o = (const float*)d_in[5];
  const float* bh2o = (const float*)d_in[6];
  float* out = (float*)d_out;
  char* ws = (char*)d_ws;

  f16*          Wfrag = (f16*)(ws + WS_WFRAG);
  float*        beff  = (float*)(ws + WS_BEFF);
  f16*          hbuf  = (f16*)(ws + WS_HBUF);
  unsigned int* bar   = (unsigned int*)(ws + WS_BAR);

  hipMemsetAsync(bar, 0, GROUPS*32*sizeof(unsigned int), stream);
  k_bias <<<5,    256, 0, stream>>>(bi2h, bh2h, bh2o, Wi2h, beff);
  k_h1   <<<1024, 256, 0, stream>>>(x0, Wi2h, bi2h, bh2h, hbuf);
  k_copy0<<<128,  256, 0, stream>>>(x0, out);
  k_wfrag<<<640,  256, 0, stream>>>(Wh2h, Wh2o, Wi2h, Wfrag);

  // 96KB dynamic LDS forces 1 block/CU (2x96KB > 160KB) -> all 256 blocks co-resident,
  // 1 wave/SIMD -> full 512-VGPR budget for the register-resident W fragments.
  hipFuncSetAttribute((const void*)k_rnn, hipFuncAttributeMaxDynamicSharedMemorySize, 98304);
  k_rnn<<<256, 256, 98304, stream>>>(Wfrag, beff, hbuf, bar, out);
}